// Round 10
// baseline (216.837 us; speedup 1.0000x reference)
//
#include <hip/hip_runtime.h>

// ---------------------------------------------------------------------------
// R_SCNN: two width-direction SCNN scans fused into one 127-step recurrence
// via MFMA, 1x1-conv channel-dot folded into the scan, then 4x bilinear
// upsample + global BN + sigmoid.
//
//   y_w = c_w + relu(M y_{w-1}),  z_w = y_w + relu(M z_{w-1}),  z_0 = y_0 = c_0
//   s[b,h,p] = dot(v, z_{127-p});  out = sigmoid(BN(upsample4(s)))
//
// Round-10 = Round-9 resubmitted (R9 failed on harness infra, not the kernel).
//  - TWO independent columns per block: 64 blocks x 8 waves; waves 0-3 and
//    4-7 run separate (b,h) columns -> 2 independent chains per SIMD fill
//    each other's stalls (m114 MFMA+VALU co-scheduling).
//  - VALU diet on the post-MFMA tail: packed-f16 carry math (cvt_pkrtz +
//    v_pk_add_f16), c staged as f16 (packed adds, half the cbuf), s-dot via
//    v_dot2_f32_f16. DPP quad_perm for the yn->zn hop (VALU pipe).
//  - staging capped at chunk 7 (chunk-8 read would be OOB past p2's last row).
// ---------------------------------------------------------------------------

typedef _Float16 f16x8 __attribute__((ext_vector_type(8)));
typedef _Float16 f16x4 __attribute__((ext_vector_type(4)));
typedef _Float16 h2    __attribute__((ext_vector_type(2)));
typedef float    f32x4 __attribute__((ext_vector_type(4)));

static __device__ __forceinline__ h2 pkrtz(float a, float b) {
  return __builtin_bit_cast(h2, __builtin_amdgcn_cvt_pkrtz(a, b));
}
static __device__ __forceinline__ float fdot2(h2 a, h2 b, float c) {
#if __has_builtin(__builtin_amdgcn_fdot2)
  return __builtin_amdgcn_fdot2(a, b, c, false);
#else
  return c + (float)a.x * (float)b.x + (float)a.y * (float)b.y;
#endif
}
// swap adjacent lane pairs (0<->1, 2<->3, ...) on the VALU pipe
static __device__ __forceinline__ int xchg_pair(int x) {
#if __has_builtin(__builtin_amdgcn_update_dpp)
  return __builtin_amdgcn_update_dpp(x, x, 0xB1, 0xF, 0xF, true); // quad_perm(1,0,3,2)
#else
  return __shfl_xor(x, 1, 64);
#endif
}

// ---- kernel 0: extract center tap of conv_w -> dense f16 [o][c], coalesced -
extern "C" __global__ void k_extract(const float* __restrict__ convw,
                                     _Float16* __restrict__ Md) {
  int q = blockIdx.x * 256 + threadIdx.x;   // 147456 float4s = 589824 floats
  float4 v = ((const float4*)convw)[q];
  float vv[4] = {v.x, v.y, v.z, v.w};
  int f = q * 4;
#pragma unroll
  for (int e = 0; e < 4; ++e) {
    int flat = f + e;                       // flat = idx*9 + 4  <=>  center tap
    if (flat % 9 == 4) Md[flat / 9] = (_Float16)vv[e];
  }
}

// ---- kernel 1: fused double scan via MFMA, 2 columns x 4 waves ------------
struct SMG {
  _Float16 cy[2][256];        // y carry (f16), ping-pong
  _Float16 pad0[32];          // 64B: cz banks offset 16 vs cy
  _Float16 cz[2][256];        // z carry (f16), ping-pong
  _Float16 pad1[32];
  _Float16 cbuf[2][16][256];  // staged c (f16), TRANSPOSED: [buf][wsub][ch]
  float    sp[128][24];       // s-dot partials (16 used; 96B rows, 16B-aligned)
};

extern "C" __global__ void __launch_bounds__(512, 2)
k_scan(const float* __restrict__ p2, const _Float16* __restrict__ Md,
       const float* __restrict__ conv1, float* __restrict__ sout,
       float* __restrict__ stats, unsigned int* __restrict__ cnt) {
  __shared__ SMG smg[2];
  const int tid  = threadIdx.x;
  const int g    = tid >> 8;        // column group 0/1 (waves 0-3 / 4-7)
  const int tg   = tid & 255;       // thread id within group
  const int l    = tid & 63;
  const int rr   = tg >> 6;         // wave in group 0..3, owns rows rr*64..+63
  const int col  = l & 15;          // MFMA n index
  const int quad = l >> 4;          // MFMA k-group / C-row-group
  const int cidx = (blockIdx.x << 1) | g;   // column 0..127
  const int bb   = cidx >> 6;
  const int hh   = cidx & 63;

  if (blockIdx.x == 0 && tid == 0) { stats[0] = 0.f; stats[1] = 0.f; *cnt = 0u; }

  SMG& sm = smg[g];
  const bool isY = (col == 0);
  const bool isZ = (col == 1);
  const int  mq  = rr * 64 + quad * 4;  // lane's row base (tile t adds t*16)

  // p2_r[b][c][h][w]: channel c at pbase + c*8192 + w
  const float* pbase = p2 + (size_t)bb * 2097152 + (size_t)hh * 128;

  // ---- stage chunk 0 (w=0..15) as f16, thread covers channel ch = tg ----
  {
    const f32x4* gp = (const f32x4*)(pbase + (size_t)tg * 8192);
    f32x4 g0 = gp[0], g1 = gp[1], g2 = gp[2], g3 = gp[3];
#pragma unroll
    for (int j = 0; j < 4; ++j) {
      sm.cbuf[0][j][tg]      = (_Float16)g0[j];
      sm.cbuf[0][4 + j][tg]  = (_Float16)g1[j];
      sm.cbuf[0][8 + j][tg]  = (_Float16)g2[j];
      sm.cbuf[0][12 + j][tg] = (_Float16)g3[j];
    }
  }

  // ---- A-fragments (resident): lane holds A[m=rr*64+t*16+col][k=ch*32+quad*8+j]
  f16x8 A[4][8];
#pragma unroll
  for (int t = 0; t < 4; ++t)
#pragma unroll
    for (int ch = 0; ch < 8; ++ch)
      A[t][ch] = *(const f16x8*)(Md + (size_t)(rr * 64 + t * 16 + col) * 256 +
                                 ch * 32 + quad * 8);

  // conv1 weights at this lane's rows, packed f16 pairs (for v_dot2)
  h2 vv01[4], vv23[4];
#pragma unroll
  for (int t = 0; t < 4; ++t) {
    f32x4 vt = *(const f32x4*)(conv1 + mq + t * 16);
    vv01[t] = pkrtz(vt[0], vt[1]);
    vv23[t] = pkrtz(vt[2], vt[3]);
  }
  __syncthreads();   // chunk 0 visible

  // ---- init: w=0 state (z_0 = y_0 = c_0) from staged chunk 0 ----
  {
    h2 c01[4], c23[4];
#pragma unroll
    for (int t = 0; t < 4; ++t) {
      const h2* cp = (const h2*)(&sm.cbuf[0][0][mq + t * 16]);  // broadcast
      c01[t] = cp[0]; c23[t] = cp[1];
    }
    if (isY) {
#pragma unroll
      for (int t = 0; t < 4; ++t) {
        int2 u = make_int2(__builtin_bit_cast(int, c01[t]),
                           __builtin_bit_cast(int, c23[t]));
        *(int2*)(sm.cy[0] + mq + t * 16) = u;
        *(int2*)(sm.cz[0] + mq + t * 16) = u;
      }
    }
    if (isZ) {
      float p = 0.f;
#pragma unroll
      for (int t = 0; t < 4; ++t) {
        p = fdot2(vv01[t], c01[t], p);
        p = fdot2(vv23[t], c23[t], p);
      }
      sm.sp[0][rr * 4 + quad] = p;
    }
  }
  __syncthreads();   // carries visible

  // B-fragment source: lane parity picks y (even cols) / z (odd cols).
  const _Float16* selA = ((l & 1) ? sm.cz[0] : sm.cy[0]) + quad * 8;  // w odd
  const _Float16* selB = ((l & 1) ? sm.cz[1] : sm.cy[1]) + quad * 8;  // w even

#define STEP(W, SELP, WY, WZ, DOSTAGE)                                         \
  do {                                                                         \
    f32x4 g0, g1, g2, g3;                                                      \
    bool stg = (DOSTAGE) && (((W) & 15) == 1) && ((W) < 98);                   \
    int t1 = ((W) >> 4) + 1;                                                   \
    if (stg) {                                                                 \
      const f32x4* gp = (const f32x4*)(pbase + (size_t)tg * 8192 + t1 * 16);   \
      g0 = gp[0]; g1 = gp[1]; g2 = gp[2]; g3 = gp[3];                          \
    }                                                                          \
    f16x8 B[8];                                                                \
    _Pragma("unroll")                                                          \
    for (int ch = 0; ch < 8; ++ch)                                             \
      B[ch] = *(const f16x8*)((SELP) + ch * 32);                               \
    f32x4 acc[4];                                                              \
    _Pragma("unroll")                                                          \
    for (int t = 0; t < 4; ++t) {                                              \
      f32x4 p0 = {0.f, 0.f, 0.f, 0.f}, p1 = {0.f, 0.f, 0.f, 0.f};             \
      p0 = __builtin_amdgcn_mfma_f32_16x16x32_f16(A[t][0], B[0], p0, 0, 0, 0); \
      p1 = __builtin_amdgcn_mfma_f32_16x16x32_f16(A[t][4], B[4], p1, 0, 0, 0); \
      p0 = __builtin_amdgcn_mfma_f32_16x16x32_f16(A[t][1], B[1], p0, 0, 0, 0); \
      p1 = __builtin_amdgcn_mfma_f32_16x16x32_f16(A[t][5], B[5], p1, 0, 0, 0); \
      p0 = __builtin_amdgcn_mfma_f32_16x16x32_f16(A[t][2], B[2], p0, 0, 0, 0); \
      p1 = __builtin_amdgcn_mfma_f32_16x16x32_f16(A[t][6], B[6], p1, 0, 0, 0); \
      p0 = __builtin_amdgcn_mfma_f32_16x16x32_f16(A[t][3], B[3], p0, 0, 0, 0); \
      p1 = __builtin_amdgcn_mfma_f32_16x16x32_f16(A[t][7], B[7], p1, 0, 0, 0); \
      acc[t] = p0 + p1;                                                        \
    }                                                                          \
    if (stg) {                                                                 \
      int bs = t1 & 1;                                                         \
      _Pragma("unroll")                                                        \
      for (int j = 0; j < 4; ++j) {                                            \
        sm.cbuf[bs][j][tg]      = (_Float16)g0[j];                             \
        sm.cbuf[bs][4 + j][tg]  = (_Float16)g1[j];                             \
        sm.cbuf[bs][8 + j][tg]  = (_Float16)g2[j];                             \
        sm.cbuf[bs][12 + j][tg] = (_Float16)g3[j];                             \
      }                                                                        \
    }                                                                          \
    const _Float16* cb = &sm.cbuf[((W) >> 4) & 1][(W) & 15][0];                \
    float p = 0.f;                                                             \
    _Pragma("unroll")                                                          \
    for (int t = 0; t < 4; ++t) {                                              \
      const h2* cp = (const h2*)(cb + mq + t * 16);     /* broadcast b64 */    \
      h2 c01 = cp[0], c23 = cp[1];                                             \
      h2 rm01 = pkrtz(fmaxf(acc[t][0], 0.f), fmaxf(acc[t][1], 0.f));           \
      h2 rm23 = pkrtz(fmaxf(acc[t][2], 0.f), fmaxf(acc[t][3], 0.f));           \
      h2 yh01 = c01 + rm01, yh23 = c23 + rm23;    /* v_pk_add_f16 */           \
      int u0 = __builtin_bit_cast(int, yh01), u1 = __builtin_bit_cast(int, yh23);\
      if (isY) *(int2*)((WY) + mq + t * 16) = make_int2(u0, u1);               \
      h2 ys01 = __builtin_bit_cast(h2, xchg_pair(u0));                         \
      h2 ys23 = __builtin_bit_cast(h2, xchg_pair(u1));                         \
      h2 zh01 = ys01 + rm01, zh23 = ys23 + rm23;                               \
      if (isZ) {                                                               \
        *(int2*)((WZ) + mq + t * 16) =                                         \
            make_int2(__builtin_bit_cast(int, zh01),                           \
                      __builtin_bit_cast(int, zh23));                          \
        p = fdot2(vv01[t], zh01, p);                                           \
        p = fdot2(vv23[t], zh23, p);                                           \
      }                                                                        \
    }                                                                          \
    if (isZ) sm.sp[(W)][rr * 4 + quad] = p;                                    \
    __syncthreads();                                                           \
  } while (0)

#pragma unroll 1
  for (int w = 1; w < 127; w += 2) {
    STEP(w,     selA, sm.cy[1], sm.cz[1], 1);  // read buf0, write buf1 (w odd)
    STEP(w + 1, selB, sm.cy[0], sm.cz[0], 0);  // read buf1, write buf0
  }
  STEP(127, selA, sm.cy[1], sm.cz[1], 0);
#undef STEP

  // s[b,h,127-w] = dot(v, z_w): reduce the 16 partials per step
  if (tg < 128) {
    const f32x4* q = (const f32x4*)(sm.sp[tg]);
    f32x4 q0 = q[0], q1 = q[1], q2 = q[2], q3 = q[3];
    float s = q0[0] + q0[1] + q0[2] + q0[3] + q1[0] + q1[1] + q1[2] + q1[3] +
              q2[0] + q2[1] + q2[2] + q2[3] + q3[0] + q3[1] + q3[2] + q3[3];
    sout[(cidx << 7) + (127 - tg)] = s;
  }
}

// ---- bilinear 4x upsample (align_corners) of s: (2,64,128) -> (2,256,512) --
static __device__ __forceinline__ float bilin(const float* __restrict__ s,
                                              int idx) {
  int bb  = idx >> 17;
  int rem = idx & 131071;
  int ho  = rem >> 9;
  int wo  = rem & 511;
  const float SY = 63.0f / 255.0f, SX = 127.0f / 511.0f;
  float fy = (float)ho * SY;
  int y0 = (int)fy; int y1 = min(y0 + 1, 63); float wy = fy - (float)y0;
  float fx = (float)wo * SX;
  int x0 = (int)fx; int x1 = min(x0 + 1, 127); float wx = fx - (float)x0;
  const float* sb = s + bb * 8192;
  float cA = sb[y0 * 128 + x0] * (1.f - wy) + sb[y1 * 128 + x0] * wy;
  float cB = sb[y0 * 128 + x1] * (1.f - wy) + sb[y1 * 128 + x1] * wy;
  return cA * (1.f - wx) + cB * wx;
}

// ---- kernel 2: fused stats + normalize + sigmoid (grid-wide via counter) ---
extern "C" __global__ void __launch_bounds__(256, 1)
k_statsnorm(const float* __restrict__ s, float* __restrict__ stats,
            unsigned int* __restrict__ cnt, const float* __restrict__ gamma,
            const float* __restrict__ beta, float* __restrict__ out) {
  int tid  = threadIdx.x;
  int base = blockIdx.x * 1024 + tid;
  float u[4];
  float sum = 0.f, ssq = 0.f;
#pragma unroll
  for (int i = 0; i < 4; ++i) {
    u[i] = bilin(s, base + i * 256);
    sum += u[i]; ssq += u[i] * u[i];
  }
#pragma unroll
  for (int off = 32; off > 0; off >>= 1) {
    sum += __shfl_xor(sum, off, 64);
    ssq += __shfl_xor(ssq, off, 64);
  }
  __shared__ float ls[4], lq[4];
  int wv = tid >> 6;
  if ((tid & 63) == 0) { ls[wv] = sum; lq[wv] = ssq; }
  __syncthreads();
  if (tid == 0) {
    float bsum = ls[0] + ls[1] + ls[2] + ls[3];
    float bssq = lq[0] + lq[1] + lq[2] + lq[3];
    __hip_atomic_fetch_add(&stats[0], bsum, __ATOMIC_RELAXED, __HIP_MEMORY_SCOPE_AGENT);
    __hip_atomic_fetch_add(&stats[1], bssq, __ATOMIC_RELAXED, __HIP_MEMORY_SCOPE_AGENT);
    __hip_atomic_fetch_add(cnt, 1u, __ATOMIC_RELEASE, __HIP_MEMORY_SCOPE_AGENT);
    while (__hip_atomic_load(cnt, __ATOMIC_ACQUIRE, __HIP_MEMORY_SCOPE_AGENT) < 256u)
      __builtin_amdgcn_s_sleep(8);
  }
  __syncthreads();
  float s0 = __hip_atomic_load(&stats[0], __ATOMIC_RELAXED, __HIP_MEMORY_SCOPE_AGENT);
  float s1 = __hip_atomic_load(&stats[1], __ATOMIC_RELAXED, __HIP_MEMORY_SCOPE_AGENT);
  const float invN = 1.f / 262144.f;
  float mean  = s0 * invN;
  float var   = s1 * invN - mean * mean;
  float scale = rsqrtf(var + 1e-5f) * gamma[0];
  float bias  = beta[0] - mean * scale;
#pragma unroll
  for (int i = 0; i < 4; ++i) {
    float x = u[i] * scale + bias;
    out[base + i * 256] = 1.f / (1.f + __expf(-x));
  }
}

// ---------------------------------------------------------------------------
extern "C" void kernel_launch(void* const* d_in, const int* in_sizes, int n_in,
                              void* d_out, int out_size, void* d_ws, size_t ws_size,
                              hipStream_t stream) {
  const float* p2    = (const float*)d_in[0];   // (2,256,64,128)
  const float* convw = (const float*)d_in[1];   // (256,256,1,9)
  const float* conv1 = (const float*)d_in[2];   // (1,256,1,1)
  const float* gamma = (const float*)d_in[3];   // (1,)
  const float* beta  = (const float*)d_in[4];   // (1,)
  float* out = (float*)d_out;                   // (2,1,256,512) fp32

  char* ws = (char*)d_ws;
  float*        s     = (float*)ws;             // 16384 floats  [0, 64KB)
  float*        stats = (float*)(ws + 65536);   // 2 floats
  unsigned int* cnt   = (unsigned int*)(ws + 65544);
  _Float16*     Md    = (_Float16*)(ws + 65792);// 65536 f16 (128 KB)

  hipLaunchKernelGGL(k_extract,   dim3(576), dim3(256), 0, stream, convw, Md);
  hipLaunchKernelGGL(k_scan,      dim3(64),  dim3(512), 0, stream,
                     p2, Md, conv1, s, stats, cnt);
  hipLaunchKernelGGL(k_statsnorm, dim3(256), dim3(256), 0, stream,
                     s, stats, cnt, gamma, beta, out);
}